// Round 3
// baseline (1235.451 us; speedup 1.0000x reference)
//
#include <hip/hip_runtime.h>
#include <hip/hip_bf16.h>

typedef __bf16 bf16;
typedef bf16 bf16x8 __attribute__((ext_vector_type(8)));
typedef float f32x4 __attribute__((ext_vector_type(4)));

struct alignas(8) bh4 { bf16 v[4]; };

// async global->LDS, 16B per lane. LDS dest must be wave-uniform base + lane*16.
__device__ __forceinline__ void glds16(const bf16* g, bf16* l) {
  __builtin_amdgcn_global_load_lds(
      (const __attribute__((address_space(1))) void*)g,
      (__attribute__((address_space(3))) void*)l, 16, 0, 0);
}

// log2(e) / sqrt(128): folded into Q so softmax uses exp2 (native v_exp_f32)
#define QSCALE (1.4426950408889634f / 11.313708498984761f)

// fp32 -> bf16 conversion (inputs are fp32 — established round 2: detector
// fired the fp32 path, NaN vanished; bf16 passthrough would have kept it).
__global__ void convert_to_bf16(const float* __restrict__ s, bf16* __restrict__ dst,
                                long n) {
  const long stride = (long)gridDim.x * blockDim.x * 8;
  for (long i = ((long)blockIdx.x * blockDim.x + threadIdx.x) * 8; i < n; i += stride) {
    float4 a = *(const float4*)(s + i);
    float4 b = *(const float4*)(s + i + 4);
    bf16x8 o;
    o[0] = (bf16)a.x; o[1] = (bf16)a.y; o[2] = (bf16)a.z; o[3] = (bf16)a.w;
    o[4] = (bf16)b.x; o[5] = (bf16)b.y; o[6] = (bf16)b.z; o[7] = (bf16)b.w;
    *(bf16x8*)(dst + i) = o;
  }
}

// ---------------- GEMM: C = A (M,K) * Bw^T, Bw is (N,K) row-major ----------
// 128x128 tile, BK=32, 4 waves 2x2 (m97-verified structure).
// MODE 0: scatter epilogue into q (scaled), k, v^T bf16 per-head buffers (N=6144).
// MODE 1: plain FP32 (M,N) output (d_out is the reference's fp32 dtype).
template <int MODE>
__global__ void gemm_bt(const bf16* __restrict__ A, const bf16* __restrict__ Bw,
                        void* __restrict__ C0v, bf16* __restrict__ C1,
                        bf16* __restrict__ C2, int M, int N, int K) {
  __shared__ __align__(16) bf16 sA[128 * 32];
  __shared__ __align__(16) bf16 sB[128 * 32];
  const int tid = threadIdx.x;
  const int lane = tid & 63, wid = tid >> 6;
  const int wm = wid & 1, wn = wid >> 1;
  const int quad = lane >> 4, l16 = lane & 15;
  const int bm = blockIdx.y * 128, bn = blockIdx.x * 128;

  f32x4 acc[4][4] = {};

  const int srow = tid >> 2, scol = (tid & 3) << 3;
  const bf16* gA = A + (size_t)(bm + srow) * K + scol;
  const bf16* gB = Bw + (size_t)(bn + srow) * K + scol;
  const size_t row64 = (size_t)64 * K;

  for (int k0 = 0; k0 < K; k0 += 32) {
    glds16(gA + k0, &sA[tid * 8]);
    glds16(gA + k0 + row64, &sA[2048 + tid * 8]);
    glds16(gB + k0, &sB[tid * 8]);
    glds16(gB + k0 + row64, &sB[2048 + tid * 8]);
    __syncthreads();
    bf16x8 af[4], bff[4];
#pragma unroll
    for (int mt = 0; mt < 4; ++mt)
      af[mt] = *(const bf16x8*)&sA[(wm * 64 + mt * 16 + l16) * 32 + quad * 8];
#pragma unroll
    for (int nt = 0; nt < 4; ++nt)
      bff[nt] = *(const bf16x8*)&sB[(wn * 64 + nt * 16 + l16) * 32 + quad * 8];
#pragma unroll
    for (int mt = 0; mt < 4; ++mt)
#pragma unroll
      for (int nt = 0; nt < 4; ++nt)
        acc[mt][nt] = __builtin_amdgcn_mfma_f32_16x16x32_bf16(af[mt], bff[nt], acc[mt][nt], 0, 0, 0);
    __syncthreads();
  }

  if (MODE == 0) {
    bf16* C0 = (bf16*)C0v;
    // N axis: [0,2048)=q, [2048,4096)=k, [4096,6144)=v; 128-col blocks never
    // straddle a (which, h) boundary.
    const int which = blockIdx.x >> 4;
    const int h = blockIdx.x & 15;
#pragma unroll
    for (int mt = 0; mt < 4; ++mt) {
      const int m0 = bm + wm * 64 + mt * 16 + quad * 4;  // token row base (4 rows)
      const int b = m0 >> 11, t0 = m0 & 2047;
#pragma unroll
      for (int nt = 0; nt < 4; ++nt) {
        const int hd = wn * 64 + nt * 16 + l16;
        if (which == 0) {
          bf16* dst = C0 + (((size_t)(b * 16 + h) * 2048 + t0) * 128 + hd);
#pragma unroll
          for (int r = 0; r < 4; ++r) dst[(size_t)r * 128] = (bf16)(acc[mt][nt][r] * QSCALE);
        } else if (which == 1) {
          bf16* dst = C1 + (((size_t)(b * 16 + h) * 2048 + t0) * 128 + hd);
#pragma unroll
          for (int r = 0; r < 4; ++r) dst[(size_t)r * 128] = (bf16)acc[mt][nt][r];
        } else {
          bh4 pk;
#pragma unroll
          for (int r = 0; r < 4; ++r) pk.v[r] = (bf16)acc[mt][nt][r];
          // V transposed: (b,h,hd,t); 4 consecutive t pack into one 8B store
          *(bh4*)(C2 + ((size_t)((b * 16 + h) * 128 + hd) * 2048 + t0)) = pk;
        }
      }
    }
  } else {
    float* C0 = (float*)C0v;  // fp32 final output
#pragma unroll
    for (int mt = 0; mt < 4; ++mt) {
      const int m0 = bm + wm * 64 + mt * 16 + quad * 4;
#pragma unroll
      for (int nt = 0; nt < 4; ++nt) {
        const int n = bn + wn * 64 + nt * 16 + l16;
#pragma unroll
        for (int r = 0; r < 4; ++r)
          C0[(size_t)(m0 + r) * N + n] = acc[mt][nt][r];
      }
    }
  }
}

// ---------------- Flash attention ----------------
// Grid: (B*H, T/128). Block 256 = 4 waves; wave w owns q-rows [w*32, w*32+32).
__global__ void attn_kernel(const bf16* __restrict__ Q, const bf16* __restrict__ Kb,
                            const bf16* __restrict__ Vt, const int* __restrict__ mask,
                            bf16* __restrict__ Y) {
  __shared__ __align__(16) bf16 sQ[128 * 136];
  __shared__ __align__(16) bf16 sKV[128 * 72];  // K tile uses 64*136=8704 <= 9216
  __shared__ __align__(16) bf16 sP[128 * 72];
  const int tid = threadIdx.x;
  const int lane = tid & 63, w = tid >> 6;
  const int quad = lane >> 4, l16 = lane & 15;
  const int bh = blockIdx.x, b = bh >> 4;
  const int qt = blockIdx.y;
  const size_t head = (size_t)bh * (2048 * 128);

  {  // stage Q tile (128 x 128), padded stride 136
    const int row = tid >> 4, col = (tid & 15) * 8;
    const bf16* g = Q + head + (size_t)(qt * 128) * 128;
#pragma unroll
    for (int p = 0; p < 8; ++p) {
      const int rr = row + p * 16;
      *(int4*)&sQ[rr * 136 + col] = *(const int4*)(g + (size_t)rr * 128 + col);
    }
  }

  f32x4 o[2][8] = {};
  float mrow[2][4], lrow[2][4];
#pragma unroll
  for (int mt = 0; mt < 2; ++mt)
#pragma unroll
    for (int r = 0; r < 4; ++r) { mrow[mt][r] = -3.0e38f; lrow[mt][r] = 0.0f; }

  for (int kt = 0; kt < 32; ++kt) {
    const int key0 = kt * 64;
    {  // stage K tile (64 keys x 128 hd), stride 136
      const int row = tid >> 4, col = (tid & 15) * 8;
      const bf16* g = Kb + head + (size_t)key0 * 128;
#pragma unroll
      for (int p = 0; p < 4; ++p) {
        const int rr = row + p * 16;
        *(int4*)&sKV[rr * 136 + col] = *(const int4*)(g + (size_t)rr * 128 + col);
      }
    }
    __syncthreads();

    // S = Q K^T  (wave: 2 m-tiles x 4 n-tiles x 4 k-steps)
    f32x4 s[2][4] = {};
#pragma unroll
    for (int kk = 0; kk < 4; ++kk) {
      bf16x8 aq[2], bk[4];
#pragma unroll
      for (int mt = 0; mt < 2; ++mt)
        aq[mt] = *(const bf16x8*)&sQ[(w * 32 + mt * 16 + l16) * 136 + kk * 32 + quad * 8];
#pragma unroll
      for (int nt = 0; nt < 4; ++nt)
        bk[nt] = *(const bf16x8*)&sKV[(nt * 16 + l16) * 136 + kk * 32 + quad * 8];
#pragma unroll
      for (int mt = 0; mt < 2; ++mt)
#pragma unroll
        for (int nt = 0; nt < 4; ++nt)
          s[mt][nt] = __builtin_amdgcn_mfma_f32_16x16x32_bf16(aq[mt], bk[nt], s[mt][nt], 0, 0, 0);
    }
    __syncthreads();  // all K reads done; sKV reusable

    {  // stage V^T tile (128 hd x 64 keys), stride 72
      const int row = tid >> 3, col = (tid & 7) * 8;
      const bf16* g = Vt + (size_t)bh * (128 * 2048) + key0;
#pragma unroll
      for (int p = 0; p < 4; ++p) {
        const int rr = row + p * 32;
        *(int4*)&sKV[rr * 72 + col] = *(const int4*)(g + (size_t)rr * 2048 + col);
      }
    }

    bool ok[4];
#pragma unroll
    for (int nt = 0; nt < 4; ++nt)
      ok[nt] = mask[b * 2048 + key0 + nt * 16 + l16] != 0;

    // online softmax; scale already folded into Q (base-2 logits)
#pragma unroll
    for (int mt = 0; mt < 2; ++mt)
#pragma unroll
      for (int r = 0; r < 4; ++r) {
        float sv[4];
#pragma unroll
        for (int nt = 0; nt < 4; ++nt) sv[nt] = ok[nt] ? s[mt][nt][r] : -1.0e30f;
        float mx = fmaxf(fmaxf(sv[0], sv[1]), fmaxf(sv[2], sv[3]));
        mx = fmaxf(mx, __shfl_xor(mx, 1));
        mx = fmaxf(mx, __shfl_xor(mx, 2));
        mx = fmaxf(mx, __shfl_xor(mx, 4));
        mx = fmaxf(mx, __shfl_xor(mx, 8));
        const float newm = fmaxf(mrow[mt][r], mx);
        const float alpha = exp2f(mrow[mt][r] - newm);
        mrow[mt][r] = newm;
        float pv[4], rs = 0.0f;
#pragma unroll
        for (int nt = 0; nt < 4; ++nt) {
          pv[nt] = ok[nt] ? exp2f(sv[nt] - newm) : 0.0f;
          rs += pv[nt];
        }
        rs += __shfl_xor(rs, 1);
        rs += __shfl_xor(rs, 2);
        rs += __shfl_xor(rs, 4);
        rs += __shfl_xor(rs, 8);
        lrow[mt][r] = lrow[mt][r] * alpha + rs;
#pragma unroll
        for (int nh = 0; nh < 8; ++nh) o[mt][nh][r] *= alpha;
        const int prow = w * 32 + mt * 16 + quad * 4 + r;  // C-layout -> P in LDS
#pragma unroll
        for (int nt = 0; nt < 4; ++nt)
          sP[prow * 72 + nt * 16 + l16] = (bf16)pv[nt];
      }
    __syncthreads();  // V^T staged (P is wave-local; per-wave DS ordering suffices)

    // O += P V  (wave: 2 m-tiles x 8 hd-tiles x 2 k-steps)
#pragma unroll
    for (int kk = 0; kk < 2; ++kk) {
      bf16x8 ap[2], bv[8];
#pragma unroll
      for (int mt = 0; mt < 2; ++mt)
        ap[mt] = *(const bf16x8*)&sP[(w * 32 + mt * 16 + l16) * 72 + kk * 32 + quad * 8];
#pragma unroll
      for (int nh = 0; nh < 8; ++nh)
        bv[nh] = *(const bf16x8*)&sKV[(nh * 16 + l16) * 72 + kk * 32 + quad * 8];
#pragma unroll
      for (int mt = 0; mt < 2; ++mt)
#pragma unroll
        for (int nh = 0; nh < 8; ++nh)
          o[mt][nh] = __builtin_amdgcn_mfma_f32_16x16x32_bf16(ap[mt], bv[nh], o[mt][nh], 0, 0, 0);
    }
    __syncthreads();  // PV reads done before next K staging
  }

  // normalize, round-trip O through sQ for coalesced (B,T,D) store
#pragma unroll
  for (int mt = 0; mt < 2; ++mt)
#pragma unroll
    for (int r = 0; r < 4; ++r) {
      const float invl = 1.0f / lrow[mt][r];
      const int prow = w * 32 + mt * 16 + quad * 4 + r;
#pragma unroll
      for (int nh = 0; nh < 8; ++nh)
        sQ[prow * 136 + nh * 16 + l16] = (bf16)(o[mt][nh][r] * invl);
    }
  __syncthreads();
  {
    const int row = tid >> 4, col = (tid & 15) * 8;
    const int h = bh & 15;
    bf16* g = Y + ((size_t)(b * 2048 + qt * 128)) * 2048 + h * 128;
#pragma unroll
    for (int p = 0; p < 8; ++p) {
      const int rr = row + p * 16;
      *(int4*)(g + (size_t)rr * 2048 + col) = *(const int4*)&sQ[rr * 136 + col];
    }
  }
}

extern "C" void kernel_launch(void* const* d_in, const int* in_sizes, int n_in,
                              void* d_out, int out_size, void* d_ws, size_t ws_size,
                              hipStream_t stream) {
  const float* x_raw  = (const float*)d_in[0];
  const int*   mask   = (const int*)d_in[1];
  const float* wq_raw = (const float*)d_in[2];
  const float* wo_raw = (const float*)d_in[3];
  float* out = (float*)d_out;  // reference output dtype is fp32

  char* ws = (char*)d_ws;
  const size_t MB = 1024 * 1024;
  bf16* xb  = (bf16*)(ws + 256);              // 32 MiB  (x bf16; later reused as yb)
  bf16* wqb = (bf16*)(ws + 256 + 32 * MB);    // 24 MiB  (w_qkv bf16; later reused as wob)
  bf16* qb  = (bf16*)(ws + 256 + 56 * MB);    // 32 MiB  (B,H,T,HD) pre-scaled
  bf16* kb  = (bf16*)(ws + 256 + 88 * MB);    // 32 MiB  (B,H,T,HD)
  bf16* vt  = (bf16*)(ws + 256 + 120 * MB);   // 32 MiB  (B,H,HD,T)
  bf16* yb  = xb;                             // attention output (B,T,D)
  bf16* wob = wqb;                            // w_o bf16 (converted after gemm1)

  convert_to_bf16<<<1024, 256, 0, stream>>>(x_raw, xb, (long)in_sizes[0]);
  convert_to_bf16<<<1024, 256, 0, stream>>>(wq_raw, wqb, (long)in_sizes[2]);

  // qkv projection (M=8192, N=6144, K=2048), scatter to per-head layouts
  gemm_bt<0><<<dim3(48, 64), 256, 0, stream>>>(xb, wqb, qb, kb, vt, 8192, 6144, 2048);

  // w_o conversion (overwrites wqb region — dead after gemm1)
  convert_to_bf16<<<1024, 256, 0, stream>>>(wo_raw, wob, (long)in_sizes[3]);

  // fused flash attention (writes yb = xb region — x dead after gemm1)
  attn_kernel<<<dim3(64, 16), 256, 0, stream>>>(qb, kb, vt, mask, yb);

  // output projection (M=8192, N=2048, K=2048), fp32 out
  gemm_bt<1><<<dim3(16, 64), 256, 0, stream>>>(yb, wob, out, nullptr, nullptr, 8192, 2048, 2048);
}

// Round 4
// 741.772 us; speedup vs baseline: 1.6655x; 1.6655x over previous
//
#include <hip/hip_runtime.h>
#include <hip/hip_bf16.h>

typedef __bf16 bf16;
typedef bf16 bf16x8 __attribute__((ext_vector_type(8)));
typedef float f32x4 __attribute__((ext_vector_type(4)));

struct alignas(8) bh4 { bf16 v[4]; };

// async global->LDS, 16B per lane. LDS dest must be wave-uniform base + lane*16.
__device__ __forceinline__ void glds16(const bf16* g, bf16* l) {
  __builtin_amdgcn_global_load_lds(
      (const __attribute__((address_space(1))) void*)g,
      (__attribute__((address_space(3))) void*)l, 16, 0, 0);
}

// log2(e) / sqrt(128): folded into Q so softmax uses exp2 (native v_exp_f32)
#define QSCALE (1.4426950408889634f / 11.313708498984761f)

// fp32 -> bf16 conversion (inputs are fp32; established round 2).
__global__ void convert_to_bf16(const float* __restrict__ s, bf16* __restrict__ dst,
                                long n) {
  const long stride = (long)gridDim.x * blockDim.x * 8;
  for (long i = ((long)blockIdx.x * blockDim.x + threadIdx.x) * 8; i < n; i += stride) {
    float4 a = *(const float4*)(s + i);
    float4 b = *(const float4*)(s + i + 4);
    bf16x8 o;
    o[0] = (bf16)a.x; o[1] = (bf16)a.y; o[2] = (bf16)a.z; o[3] = (bf16)a.w;
    o[4] = (bf16)b.x; o[5] = (bf16)b.y; o[6] = (bf16)b.z; o[7] = (bf16)b.w;
    *(bf16x8*)(dst + i) = o;
  }
}

// ---------------- GEMM: C = A (M,K) * Bw^T, Bw is (N,K) row-major ----------
// 128x128 tile, BK=32, 4 waves 2x2 (verified round 3).
template <int MODE>
__global__ void gemm_bt(const bf16* __restrict__ A, const bf16* __restrict__ Bw,
                        void* __restrict__ C0v, bf16* __restrict__ C1,
                        bf16* __restrict__ C2, int M, int N, int K) {
  __shared__ __align__(16) bf16 sA[128 * 32];
  __shared__ __align__(16) bf16 sB[128 * 32];
  const int tid = threadIdx.x;
  const int lane = tid & 63, wid = tid >> 6;
  const int wm = wid & 1, wn = wid >> 1;
  const int quad = lane >> 4, l16 = lane & 15;
  const int bm = blockIdx.y * 128, bn = blockIdx.x * 128;

  f32x4 acc[4][4] = {};

  const int srow = tid >> 2, scol = (tid & 3) << 3;
  const bf16* gA = A + (size_t)(bm + srow) * K + scol;
  const bf16* gB = Bw + (size_t)(bn + srow) * K + scol;
  const size_t row64 = (size_t)64 * K;

  for (int k0 = 0; k0 < K; k0 += 32) {
    glds16(gA + k0, &sA[tid * 8]);
    glds16(gA + k0 + row64, &sA[2048 + tid * 8]);
    glds16(gB + k0, &sB[tid * 8]);
    glds16(gB + k0 + row64, &sB[2048 + tid * 8]);
    __syncthreads();
    bf16x8 af[4], bff[4];
#pragma unroll
    for (int mt = 0; mt < 4; ++mt)
      af[mt] = *(const bf16x8*)&sA[(wm * 64 + mt * 16 + l16) * 32 + quad * 8];
#pragma unroll
    for (int nt = 0; nt < 4; ++nt)
      bff[nt] = *(const bf16x8*)&sB[(wn * 64 + nt * 16 + l16) * 32 + quad * 8];
#pragma unroll
    for (int mt = 0; mt < 4; ++mt)
#pragma unroll
      for (int nt = 0; nt < 4; ++nt)
        acc[mt][nt] = __builtin_amdgcn_mfma_f32_16x16x32_bf16(af[mt], bff[nt], acc[mt][nt], 0, 0, 0);
    __syncthreads();
  }

  if (MODE == 0) {
    bf16* C0 = (bf16*)C0v;
    const int which = blockIdx.x >> 4;
    const int h = blockIdx.x & 15;
#pragma unroll
    for (int mt = 0; mt < 4; ++mt) {
      const int m0 = bm + wm * 64 + mt * 16 + quad * 4;
      const int b = m0 >> 11, t0 = m0 & 2047;
#pragma unroll
      for (int nt = 0; nt < 4; ++nt) {
        const int hd = wn * 64 + nt * 16 + l16;
        if (which == 0) {
          bf16* dst = C0 + (((size_t)(b * 16 + h) * 2048 + t0) * 128 + hd);
#pragma unroll
          for (int r = 0; r < 4; ++r) dst[(size_t)r * 128] = (bf16)(acc[mt][nt][r] * QSCALE);
        } else if (which == 1) {
          bf16* dst = C1 + (((size_t)(b * 16 + h) * 2048 + t0) * 128 + hd);
#pragma unroll
          for (int r = 0; r < 4; ++r) dst[(size_t)r * 128] = (bf16)acc[mt][nt][r];
        } else {
          bh4 pk;
#pragma unroll
          for (int r = 0; r < 4; ++r) pk.v[r] = (bf16)acc[mt][nt][r];
          *(bh4*)(C2 + ((size_t)((b * 16 + h) * 128 + hd) * 2048 + t0)) = pk;
        }
      }
    }
  } else {
    float* C0 = (float*)C0v;  // fp32 final output
#pragma unroll
    for (int mt = 0; mt < 4; ++mt) {
      const int m0 = bm + wm * 64 + mt * 16 + quad * 4;
#pragma unroll
      for (int nt = 0; nt < 4; ++nt) {
        const int n = bn + wn * 64 + nt * 16 + l16;
#pragma unroll
        for (int r = 0; r < 4; ++r)
          C0[(size_t)(m0 + r) * N + n] = acc[mt][nt][r];
      }
    }
  }
}

// ---------------- Flash attention, transposed-S formulation ----------------
// S^T = K·Q^T (m=key, n=query) so softmax reduces along quad/register axes:
// 2 shuffles per reduction instead of 4, P^T written as 8B packs.
// O^T = V^T·P^T (m=hd, n=query). Q resident in registers (B-operand layout).
// K/V staged via glds16 with XOR chunk swizzle (c' = c ^ (row&7)) so the
// unpadded tiles read conflict-free. Grid (B*H, T/128), 256 thr = 4 waves,
// wave w owns queries [w*32, w*32+32). LDS 50 KB -> 3 blocks/CU.
__global__ __launch_bounds__(256, 3)
void attn_kernel(const bf16* __restrict__ Q, const bf16* __restrict__ Kb,
                 const bf16* __restrict__ Vt, const int* __restrict__ mask,
                 bf16* __restrict__ Y) {
  __shared__ __align__(16) bf16 smem[25600];  // 51200 B
  bf16* sK = smem;                 // 64 keys x 128 hd (swizzled chunks), 16 KB
  bf16* sV = smem + 8192;          // 128 hd x 64 keys (swizzled chunks), 16 KB
  bf16* sP = smem + 16384;         // per-wave 32 queries x 72 (pad), 18 KB

  const int tid = threadIdx.x;
  const int lane = tid & 63, w = tid >> 6;
  const int quad = lane >> 4, l16 = lane & 15;
  const int bh = blockIdx.x, b = bh >> 4, h = bh & 15;
  const int qt = blockIdx.y;
  const size_t head = (size_t)bh * (2048 * 128);

  // Q fragments resident: B-operand layout (lane = query, k = quad*8+j)
  bf16x8 qf[2][4];
#pragma unroll
  for (int nt = 0; nt < 2; ++nt) {
    const int t = qt * 128 + w * 32 + nt * 16 + l16;
    const bf16* g = Q + head + (size_t)t * 128 + quad * 8;
#pragma unroll
    for (int kk = 0; kk < 4; ++kk)
      qf[nt][kk] = *(const bf16x8*)(g + kk * 32);
  }

  f32x4 o[8][2] = {};                       // O^T: rows hd (8 tiles), cols query
  float mrow[2] = {-3.0e38f, -3.0e38f};
  float lrow[2] = {0.0f, 0.0f};

  const int* maskb = mask + b * 2048;
  bf16* sPw = sP + w * (32 * 72);

  for (int kt = 0; kt < 32; ++kt) {
    const int key0 = kt * 64;
    {  // stage K tile (64 keys x 128 hd = 16 chunks/row), swizzled
      const int cp = lane & 15;
      const int rbase = w * 16 + (lane >> 4);
#pragma unroll
      for (int p = 0; p < 4; ++p) {
        const int row = rbase + p * 4;
        const int c = (cp & 8) | ((cp ^ row) & 7);
        glds16(Kb + head + (size_t)(key0 + row) * 128 + c * 8,
               &sK[(w * 16 + p * 4) * 128 + lane * 8]);
      }
    }
    {  // stage V^T tile (128 hd x 64 keys = 8 chunks/row), swizzled
      const int cp = lane & 7;
      const int rbase = w * 32 + (lane >> 3);
#pragma unroll
      for (int p = 0; p < 4; ++p) {
        const int row = rbase + p * 8;
        const int c = cp ^ (row & 7);
        glds16(Vt + head + (size_t)row * 2048 + key0 + c * 8,
               &sV[(w * 32 + p * 8) * 64 + lane * 8]);
      }
    }
    __syncthreads();

    // S^T = K · Q^T : st[mt=key-tile][nt=query-tile]
    f32x4 st[4][2] = {};
#pragma unroll
    for (int kk = 0; kk < 4; ++kk) {
      bf16x8 ak[4];
#pragma unroll
      for (int mt = 0; mt < 4; ++mt) {
        const int row = mt * 16 + l16;
        const int c = kk * 4 + quad;
        const int cp = (c & 8) | ((c ^ row) & 7);
        ak[mt] = *(const bf16x8*)&sK[row * 128 + cp * 8];
      }
#pragma unroll
      for (int mt = 0; mt < 4; ++mt)
#pragma unroll
        for (int nt = 0; nt < 2; ++nt)
          st[mt][nt] = __builtin_amdgcn_mfma_f32_16x16x32_bf16(ak[mt], qf[nt][kk], st[mt][nt], 0, 0, 0);
    }

    // mask for this wave's keys: key = 16*mt + 4*quad + r
    const int4* mp = (const int4*)(maskb + key0);
    int4 mm[4];
#pragma unroll
    for (int mt = 0; mt < 4; ++mt) mm[mt] = mp[mt * 4 + quad];

    // online softmax per query column (2 per lane); reductions = 2 shuffles
#pragma unroll
    for (int nt = 0; nt < 2; ++nt) {
      float mx = -1.0e30f;
#pragma unroll
      for (int mt = 0; mt < 4; ++mt) {
        const int* mi = (const int*)&mm[mt];
#pragma unroll
        for (int r = 0; r < 4; ++r) {
          float v = (mi[r] != 0) ? st[mt][nt][r] : -1.0e30f;
          st[mt][nt][r] = v;
          mx = fmaxf(mx, v);
        }
      }
      mx = fmaxf(mx, __shfl_xor(mx, 16));
      mx = fmaxf(mx, __shfl_xor(mx, 32));
      const float newm = fmaxf(mrow[nt], mx);
      const float alpha = exp2f(mrow[nt] - newm);
      mrow[nt] = newm;
      float rs = 0.0f;
#pragma unroll
      for (int mt = 0; mt < 4; ++mt) {
        const int* mi = (const int*)&mm[mt];
        bh4 pk;
#pragma unroll
        for (int r = 0; r < 4; ++r) {
          const float p = (mi[r] != 0) ? exp2f(st[mt][nt][r] - newm) : 0.0f;
          rs += p;
          pk.v[r] = (bf16)p;
        }
        // P^T[key][query] stored row-major by query, stride 72 (pad)
        *(bh4*)&sPw[(nt * 16 + l16) * 72 + mt * 16 + quad * 4] = pk;
      }
      rs += __shfl_xor(rs, 16);
      rs += __shfl_xor(rs, 32);
      lrow[nt] = lrow[nt] * alpha + rs;
#pragma unroll
      for (int mt = 0; mt < 8; ++mt)
#pragma unroll
        for (int r = 0; r < 4; ++r)
          o[mt][nt][r] *= alpha;
    }

    // O^T += V^T · P^T  (wave-local sP: same-wave ds ordering suffices)
#pragma unroll
    for (int kk = 0; kk < 2; ++kk) {
      bf16x8 bp[2];
#pragma unroll
      for (int nt = 0; nt < 2; ++nt)
        bp[nt] = *(const bf16x8*)&sPw[(nt * 16 + l16) * 72 + kk * 32 + quad * 8];
#pragma unroll
      for (int mt = 0; mt < 8; ++mt) {
        const int row = mt * 16 + l16;
        const int c = kk * 4 + quad;
        bf16x8 av = *(const bf16x8*)&sV[row * 64 + (c ^ (row & 7)) * 8];
#pragma unroll
        for (int nt = 0; nt < 2; ++nt)
          o[mt][nt] = __builtin_amdgcn_mfma_f32_16x16x32_bf16(av, bp[nt], o[mt][nt], 0, 0, 0);
      }
    }
    __syncthreads();  // sK/sV reads done before next staging
  }

  // epilogue: normalize, transpose O^T->O via per-wave LDS region, 16B stores
  bf16* sOw = smem + w * 4352;  // 32 rows x 136 stride (17408 elems total <= 25600)
#pragma unroll
  for (int nt = 0; nt < 2; ++nt) {
    const float inv = 1.0f / lrow[nt];
#pragma unroll
    for (int mt = 0; mt < 8; ++mt) {
      bh4 pk;
#pragma unroll
      for (int r = 0; r < 4; ++r) pk.v[r] = (bf16)(o[mt][nt][r] * inv);
      *(bh4*)&sOw[(nt * 16 + l16) * 136 + mt * 16 + quad * 4] = pk;
    }
  }
  // same-wave write->read: lgkmcnt ordering suffices, no barrier
  {
    const int col = (lane & 15) * 8;
#pragma unroll
    for (int p = 0; p < 8; ++p) {
      const int row = p * 4 + (lane >> 4);
      int4 v = *(const int4*)&sOw[row * 136 + col];
      const int token = qt * 128 + w * 32 + row;
      *(int4*)(Y + ((size_t)(b * 2048 + token)) * 2048 + h * 128 + col) = v;
    }
  }
}

extern "C" void kernel_launch(void* const* d_in, const int* in_sizes, int n_in,
                              void* d_out, int out_size, void* d_ws, size_t ws_size,
                              hipStream_t stream) {
  const float* x_raw  = (const float*)d_in[0];
  const int*   mask   = (const int*)d_in[1];
  const float* wq_raw = (const float*)d_in[2];
  const float* wo_raw = (const float*)d_in[3];
  float* out = (float*)d_out;  // reference output dtype is fp32

  char* ws = (char*)d_ws;
  const size_t MB = 1024 * 1024;
  bf16* xb  = (bf16*)(ws + 256);              // 32 MiB  (x bf16; later reused as yb)
  bf16* wqb = (bf16*)(ws + 256 + 32 * MB);    // 24 MiB  (w_qkv bf16; later reused as wob)
  bf16* qb  = (bf16*)(ws + 256 + 56 * MB);    // 32 MiB  (B,H,T,HD) pre-scaled
  bf16* kb  = (bf16*)(ws + 256 + 88 * MB);    // 32 MiB  (B,H,T,HD)
  bf16* vt  = (bf16*)(ws + 256 + 120 * MB);   // 32 MiB  (B,H,HD,T)
  bf16* yb  = xb;                             // attention output (B,T,D)
  bf16* wob = wqb;                            // w_o bf16 (converted after gemm1)

  convert_to_bf16<<<1024, 256, 0, stream>>>(x_raw, xb, (long)in_sizes[0]);
  convert_to_bf16<<<1024, 256, 0, stream>>>(wq_raw, wqb, (long)in_sizes[2]);

  // qkv projection (M=8192, N=6144, K=2048), scatter to per-head layouts
  gemm_bt<0><<<dim3(48, 64), 256, 0, stream>>>(xb, wqb, qb, kb, vt, 8192, 6144, 2048);

  // w_o conversion (overwrites wqb region — dead after gemm1)
  convert_to_bf16<<<1024, 256, 0, stream>>>(wo_raw, wob, (long)in_sizes[3]);

  // fused flash attention (writes yb = xb region — x dead after gemm1)
  attn_kernel<<<dim3(64, 16), 256, 0, stream>>>(qb, kb, vt, mask, yb);

  // output projection (M=8192, N=2048, K=2048), fp32 out
  gemm_bt<1><<<dim3(16, 64), 256, 0, stream>>>(yb, wob, out, nullptr, nullptr, 8192, 2048, 2048);
}